// Round 1
// baseline (397.500 us; speedup 1.0000x reference)
//
#include <hip/hip_runtime.h>
#include <hip/hip_bf16.h>
#include <math.h>

#define N_AC  8192
#define N_BC  8192
#define T_K   52
#define T_PAD 64

typedef __bf16 bf16x8 __attribute__((ext_vector_type(8)));
typedef float  f32x4  __attribute__((ext_vector_type(4)));

// ---------------------------------------------------------------------------
// Prep: x (N_BC, T_K) fp32  ->  xT (T_PAD, N_BC) bf16, zero-padded t in [52,64)
// xT row-major by t so that MFMA B-fragments (8 consecutive k for a fixed t)
// are 16B-contiguous loads.
// ---------------------------------------------------------------------------
__global__ void xpose_kernel(const float* __restrict__ x, __bf16* __restrict__ xT) {
    int b = blockIdx.x * blockDim.x + threadIdx.x;
    if (b >= N_BC) return;
    #pragma unroll
    for (int t = 0; t < T_PAD; ++t) {
        float v = (t < T_K) ? x[b * T_K + t] : 0.0f;
        xT[(size_t)t * N_BC + b] = (__bf16)v;
    }
}

// ---------------------------------------------------------------------------
// Main: per workgroup (256 thr = 4 waves) 16 AC rows.
// Waves split K into 4 segments of 2048; each wave computes a 16x64 (rows x t)
// partial y via mfma_f32_16x16x32_bf16, applies the temporal kernel weighting,
// reduces, and wave partials are combined in LDS; fused sigmoid epilogue.
//
// Fragment layouts (gfx950, 16x16x32 bf16, measured m89/m118):
//   A: lane holds A[m = lane&15][k = (lane>>4)*8 + j], j=0..7
//   B: lane holds B[k = (lane>>4)*8 + j][n = lane&15]
//   D: lane holds D[row = (lane>>4)*4 + r][col = lane&15]
// ---------------------------------------------------------------------------
__global__ __launch_bounds__(256) void ac_feedback_kernel(
    const float*  __restrict__ W,      // (N_AC, N_BC) fp32
    const __bf16* __restrict__ xT,     // (T_PAD, N_BC) bf16
    const float*  __restrict__ kern,   // (N_AC, T_K) fp32
    const float*  __restrict__ slope,  // (N_AC,)
    const float*  __restrict__ offs,   // (N_AC,)
    float*        __restrict__ out)    // (N_AC,)
{
    const int lane = threadIdx.x & 63;
    const int wave = threadIdx.x >> 6;
    const int quad = lane >> 4;
    const int l15  = lane & 15;
    const int a0   = blockIdx.x * 16;   // AC row base for this WG

    const float* wrow = W + (size_t)(a0 + l15) * N_BC;  // A row this lane feeds

    f32x4 acc[4] = {};  // 4 n-tiles: t in [0,16),[16,32),[32,48),[48,64)

    const int kseg = N_BC / 4;          // 2048 per wave
    const int kbeg = wave * kseg;
    const int koff = quad * 8;

    #pragma unroll 4
    for (int k = kbeg; k < kbeg + kseg; k += 32) {
        const float* wp = wrow + k + koff;
        float4 w0 = *(const float4*)(wp);
        float4 w1 = *(const float4*)(wp + 4);
        bf16x8 af;
        af[0] = (__bf16)w0.x; af[1] = (__bf16)w0.y;
        af[2] = (__bf16)w0.z; af[3] = (__bf16)w0.w;
        af[4] = (__bf16)w1.x; af[5] = (__bf16)w1.y;
        af[6] = (__bf16)w1.z; af[7] = (__bf16)w1.w;
        #pragma unroll
        for (int nt = 0; nt < 4; ++nt) {
            bf16x8 bf = *(const bf16x8*)(xT + (size_t)(nt * 16 + l15) * N_BC + k + koff);
            acc[nt] = __builtin_amdgcn_mfma_f32_16x16x32_bf16(af, bf, acc[nt], 0, 0, 0);
        }
    }

    // Temporal weighting: p[r] = sum_t kern[a0+quad*4+r, t] * y[row, t]
    // (this lane holds cols t = nt*16 + l15 for rows quad*4 + 0..3)
    float p[4] = {0.f, 0.f, 0.f, 0.f};
    #pragma unroll
    for (int nt = 0; nt < 4; ++nt) {
        int t = nt * 16 + l15;
        if (t < T_K) {
            #pragma unroll
            for (int r = 0; r < 4; ++r) {
                int grow = a0 + quad * 4 + r;
                p[r] += acc[nt][r] * kern[grow * T_K + t];
            }
        }
    }

    // Reduce across the 16 column-lanes (low 4 lane bits)
    #pragma unroll
    for (int m = 1; m <= 8; m <<= 1) {
        #pragma unroll
        for (int r = 0; r < 4; ++r) p[r] += __shfl_xor(p[r], m);
    }

    // Combine the 4 K-split wave partials in LDS
    __shared__ float red[4][16];
    if (l15 == 0) {
        #pragma unroll
        for (int r = 0; r < 4; ++r) red[wave][quad * 4 + r] = p[r];
    }
    __syncthreads();

    if (threadIdx.x < 16) {
        int a = a0 + threadIdx.x;
        float s = red[0][threadIdx.x] + red[1][threadIdx.x]
                + red[2][threadIdx.x] + red[3][threadIdx.x];
        float z = slope[a] * (s - offs[a]);
        out[a] = 1.0f / (1.0f + __expf(-z));
    }
}

extern "C" void kernel_launch(void* const* d_in, const int* in_sizes, int n_in,
                              void* d_out, int out_size, void* d_ws, size_t ws_size,
                              hipStream_t stream) {
    const float* x     = (const float*)d_in[0];  // (N_BC, T_K)
    const float* W     = (const float*)d_in[1];  // (N_AC, N_BC)
    const float* kern  = (const float*)d_in[2];  // (N_AC, T_K)
    const float* slope = (const float*)d_in[3];  // (N_AC,)
    const float* offs  = (const float*)d_in[4];  // (N_AC,)
    float* out = (float*)d_out;

    __bf16* xT = (__bf16*)d_ws;  // T_PAD * N_BC bf16 = 1 MB

    xpose_kernel<<<dim3(N_BC / 256), dim3(256), 0, stream>>>(x, xT);
    ac_feedback_kernel<<<dim3(N_AC / 16), dim3(256), 0, stream>>>(
        W, xT, kern, slope, offs, out);
}